// Round 10
// baseline (295.766 us; speedup 1.0000x reference)
//
#include <hip/hip_runtime.h>

#define NSEQ   8
#define HEADS  16
#define HSIZE  128          // head_size = 2048/16
#define HIDDEN 2048
#define BM     128          // row-strip height
#define BN     64           // column tile width (halved: finer bursts)
#define LDS_PAD 8
#define LDS_ROW (HSIZE + LDS_PAD)   // 136 shorts = 272 B stride (2-way alias free, m136)

typedef __attribute__((ext_vector_type(8))) short  bf16x8;
typedef __attribute__((ext_vector_type(4))) float  f32x4;

struct SeqMap {
    int       s[NSEQ];
    int       row_off[NSEQ];     // input row offset (original concat order)
    long long out_off[NSEQ];     // output element offset (original concat order)
    int       t[NSEQ];           // 128-row strips = s/128
    int       blk_start[NSEQ];   // first block id (sorted-desc-by-t order)
    int       nblk;
};

__device__ __forceinline__ unsigned short f2bf(float x) {
    // RNE fp32 -> bf16 (proven: absmax 1.22e-4)
    unsigned int u = __builtin_bit_cast(unsigned int, x);
    u += 0x7fffu + ((u >> 16) & 1u);
    return (unsigned short)(u >> 16);
}

__device__ __forceinline__ ushort4 f2bf4(float4 v) {
    ushort4 p;
    p.x = f2bf(v.x); p.y = f2bf(v.y); p.z = f2bf(v.z); p.w = f2bf(v.w);
    return p;
}

// r3 skeleton (loads top / MFMA / cvt+ds_write / stores / __syncthreads),
// geometry tuned: BN=64 double-buffer (34.8 KB LDS -> 3 blocks/CU), A in regs.
__global__ __launch_bounds__(256, 3) void qkt_strip64_kernel(
    const float* __restrict__ A, const float* __restrict__ B,
    float* __restrict__ out, SeqMap map)
{
    __shared__ unsigned short lds[2][BN * LDS_ROW];   // 2 x 17408 B = 34816 B

    // bijective XCD chunk swizzle (nblk % 8 == 0)
    const int cpx = map.nblk >> 3;
    const int bid = ((int)blockIdx.x % 8) * cpx + ((int)blockIdx.x / 8);

    // ---- block -> (seq entry i, head h, row-strip tr) ----
    int i = 0;
    #pragma unroll
    for (int k = 1; k < NSEQ; ++k) if (bid >= map.blk_start[k]) i = k;
    const int local = bid - map.blk_start[i];
    const int t     = map.t[i];
    const int h     = local / t;
    const int tr    = local - h * t;
    const int s     = map.s[i];
    const int row0  = map.row_off[i];
    const int t2    = t * 2;             // 64-wide column tiles

    const int tid  = threadIdx.x;
    const int r0   = tid >> 5;           // staging row base (0..7), rows step by 8
    const int c4   = tid & 31;           // staging float4 column
    const size_t hcol = (size_t)h * HSIZE + (size_t)c4 * 4;

    const int lane = tid & 63;
    const int w    = tid >> 6;
    const int wr   = w >> 1;             // wave row half (rows wr*64..+63)
    const int wc   = w & 1;              // wave col half (cols wc*32..+31)
    const int lrow = lane & 15;
    const int kgrp = lane >> 4;          // k sub-offset *8

    unsigned short* ldsw0 = &lds[0][r0 * LDS_ROW + c4 * 4];
    unsigned short* ldsw1 = &lds[1][r0 * LDS_ROW + c4 * 4];

    // ---- prologue: A strip rows 0-63 -> lds0, 64-127 -> lds1; af -> regs ----
    {
        const float* sa = A + (size_t)(row0 + tr * BM + r0) * HIDDEN + hcol;
        float4 ga[8], gb[8];
        #pragma unroll
        for (int it = 0; it < 8; ++it) ga[it] = *(const float4*)(sa + (size_t)it * 8 * HIDDEN);
        #pragma unroll
        for (int it = 0; it < 8; ++it) gb[it] = *(const float4*)(sa + (size_t)(64 + it * 8) * HIDDEN);
        #pragma unroll
        for (int it = 0; it < 8; ++it)
            *(ushort4*)(ldsw0 + it * 8 * LDS_ROW) = f2bf4(ga[it]);
        #pragma unroll
        for (int it = 0; it < 8; ++it)
            *(ushort4*)(ldsw1 + it * 8 * LDS_ROW) = f2bf4(gb[it]);
    }
    __syncthreads();

    bf16x8 af[4][4];     // wave's A rows: wr*64 + m*16 + lrow  (buffer = wr)
    #pragma unroll
    for (int m = 0; m < 4; ++m)
        #pragma unroll
        for (int kk = 0; kk < 4; ++kk)
            af[m][kk] = *(const bf16x8*)&lds[wr][(m*16 + lrow) * LDS_ROW + kk*32 + kgrp*8];
    __syncthreads();     // all af reads done -> buffers reusable for B

    // ---- stage B tile 0 -> lds[0] ----
    {
        const float* sb = B + (size_t)(row0 + r0) * HIDDEN + hcol;
        float4 gb[8];
        #pragma unroll
        for (int it = 0; it < 8; ++it) gb[it] = *(const float4*)(sb + (size_t)it * 8 * HIDDEN);
        #pragma unroll
        for (int it = 0; it < 8; ++it)
            *(ushort4*)(ldsw0 + it * 8 * LDS_ROW) = f2bf4(gb[it]);
    }
    __syncthreads();

    // Swapped-operand C/D layout (verified r4): lane holds C row
    // (tr*BM + wr*64 + m*16 + lrow), cols (tc*BN + wc*32 + n*16 + kgrp*4..+3).
    const long long obase = map.out_off[i] + (long long)h * s * s;
    float* orow = out + obase
                + (long long)(tr * BM + wr * 64 + lrow) * s
                + (wc * 32 + kgrp * 4);
    const long long s16 = (long long)s * 16;

    const float* sbnext = B + (size_t)(row0 + BN + r0) * HIDDEN + hcol; // tile 1

    for (int tc = 0; tc < t2; ++tc) {
        const bool has_next = (tc + 1 < t2);
        const int  cur = tc & 1;

        // 1) issue next B-tile loads (latency hides under MFMA)
        float4 g[8];
        if (has_next) {
            #pragma unroll
            for (int it = 0; it < 8; ++it) g[it] = *(const float4*)(sbnext + (size_t)it * 8 * HIDDEN);
            sbnext += (size_t)BN * HIDDEN;
        }

        // 2) MFMA from lds[cur] (operands swapped: D rows follow lrow)
        f32x4 acc[4][2];
        #pragma unroll
        for (int m = 0; m < 4; ++m)
            #pragma unroll
            for (int n = 0; n < 2; ++n)
                acc[m][n] = (f32x4){0.f, 0.f, 0.f, 0.f};

        const unsigned short* lb = &lds[cur][0];
        #pragma unroll
        for (int kk = 0; kk < 4; ++kk) {
            bf16x8 bfr[2];
            #pragma unroll
            for (int n = 0; n < 2; ++n)
                bfr[n] = *(const bf16x8*)&lb[(wc*32 + n*16 + lrow) * LDS_ROW + kk*32 + kgrp*8];
            #pragma unroll
            for (int m = 0; m < 4; ++m)
                #pragma unroll
                for (int n = 0; n < 2; ++n)
                    acc[m][n] = __builtin_amdgcn_mfma_f32_16x16x32_bf16(
                                    bfr[n], af[m][kk], acc[m][n], 0, 0, 0);
        }

        // 3) cvt + write next B tile into the other buffer
        if (has_next) {
            unsigned short* dst = cur ? ldsw0 : ldsw1;
            #pragma unroll
            for (int it = 0; it < 8; ++it)
                *(ushort4*)(dst + it * 8 * LDS_ROW) = f2bf4(g[it]);
        }

        // 4) store C tile: 8 x global_store_dwordx4 per thread
        {
            float* op = orow + tc * BN;
            #pragma unroll
            for (int m = 0; m < 4; ++m)
                #pragma unroll
                for (int n = 0; n < 2; ++n)
                    *(f32x4*)(op + (long long)m * s16 + n * 16) = acc[m][n];
        }

        __syncthreads();   // drain: keeps vmem queue shallow (r3-proven pacing)
    }
}

extern "C" void kernel_launch(void* const* d_in, const int* in_sizes, int n_in,
                              void* d_out, int out_size, void* d_ws, size_t ws_size,
                              hipStream_t stream) {
    const float* A = (const float*)d_in[0];
    const float* B = (const float*)d_in[1];
    float* out = (float*)d_out;

    static const int S[NSEQ] = {1024, 768, 512, 1536, 256, 1280, 512, 1024};

    // offsets in ORIGINAL concat order
    int row_off[NSEQ]; long long out_off[NSEQ];
    int row = 0; long long o = 0;
    for (int i = 0; i < NSEQ; ++i) {
        row_off[i] = row; out_off[i] = o;
        row += S[i];
        o   += (long long)HEADS * S[i] * S[i];
    }

    // block order: descending t (long strips dispatch first -> no tail)
    static const int order[NSEQ] = {3, 5, 0, 7, 1, 2, 6, 4};

    SeqMap map;
    int blk = 0;
    for (int k = 0; k < NSEQ; ++k) {
        const int i = order[k];
        const int t = S[i] / BM;
        map.s[k]         = S[i];
        map.row_off[k]   = row_off[i];
        map.out_off[k]   = out_off[i];
        map.t[k]         = t;
        map.blk_start[k] = blk;
        blk += HEADS * t;
    }
    map.nblk = blk;   // 864, % 8 == 0

    qkt_strip64_kernel<<<blk, 256, 0, stream>>>(A, B, out, map);
}

// Round 11
// 246.231 us; speedup vs baseline: 1.2012x; 1.2012x over previous
//
#include <hip/hip_runtime.h>

#define NSEQ   8
#define HEADS  16
#define HSIZE  128          // head_size = 2048/16
#define HIDDEN 2048
#define BT     128          // tile edge
#define TOTAL  6912         // sum(seqlen)
#define LDS_PAD 8
#define LDS_ROW (HSIZE + LDS_PAD)   // 136 shorts = 272 B stride

typedef __attribute__((ext_vector_type(8))) short  bf16x8;
typedef __attribute__((ext_vector_type(4))) float  f32x4;

struct SeqMap {
    int       s[NSEQ];
    int       row_off[NSEQ];
    long long out_off[NSEQ];
    int       t[NSEQ];
    int       blk_start[NSEQ];
    int       nblk;
};

__device__ __forceinline__ unsigned short f2bf(float x) {
    unsigned int u = __builtin_bit_cast(unsigned int, x);
    u += 0x7fffu + ((u >> 16) & 1u);
    return (unsigned short)(u >> 16);
}

__device__ __forceinline__ ushort4 f2bf4(float4 v) {
    ushort4 p;
    p.x = f2bf(v.x); p.y = f2bf(v.y); p.z = f2bf(v.z); p.w = f2bf(v.w);
    return p;
}

// ---- pass 1: f32 [TOTAL][2048] -> bf16 ws [head][TOTAL][128] (head-major) ----
// Each (head,seq) panel becomes fully linear: a 128x128 tile = one 32 KB block.
__global__ __launch_bounds__(256) void precvt_kernel(
    const float* __restrict__ A, const float* __restrict__ B,
    unsigned short* __restrict__ Aws, unsigned short* __restrict__ Bws)
{
    const int n4 = TOTAL * (HIDDEN / 4);           // float4 units per matrix
    for (int idx = blockIdx.x * 256 + threadIdx.x; idx < 2 * n4;
         idx += gridDim.x * 256) {
        const int m = idx >= n4;
        const int j = m ? idx - n4 : idx;
        const float* src = m ? B : A;
        unsigned short* dst = m ? Bws : Aws;
        float4 v = *(const float4*)(src + (size_t)j * 4);
        const int row = j >> 9;                    // / (2048/4)
        const int col = (j & 511) * 4;
        const int h   = col >> 7;
        const int cin = col & 127;
        *(ushort4*)(dst + ((size_t)h * TOTAL + row) * HSIZE + cin) = f2bf4(v);
    }
}

// ---- pass 2: r3-strip skeleton, staging from pre-converted bf16 ws ----
// Per-tile loop: 8x uint4 linear loads -> MFMA -> 8x ds_write_b128 -> scalar
// stores (r3's proven unswapped pattern) -> __syncthreads.
__global__ __launch_bounds__(256, 2) void qkt_bf16_kernel(
    const unsigned short* __restrict__ Aws, const unsigned short* __restrict__ Bws,
    float* __restrict__ out, SeqMap map)
{
    __shared__ unsigned short lds[2][BT * LDS_ROW];   // 69632 B -> 2 blocks/CU

    const int cpx = map.nblk >> 3;
    const int bid = ((int)blockIdx.x % 8) * cpx + ((int)blockIdx.x / 8);

    int i = 0;
    #pragma unroll
    for (int k = 1; k < NSEQ; ++k) if (bid >= map.blk_start[k]) i = k;
    const int local = bid - map.blk_start[i];
    const int t     = map.t[i];
    const int h     = local / t;
    const int tr    = local - h * t;
    const int s     = map.s[i];
    const int row0  = map.row_off[i];

    const int tid = threadIdx.x;
    const int r0  = tid >> 4;            // staging row within 16-row group
    const int c8  = tid & 15;            // ushort8 column

    const int lane = tid & 63;
    const int w    = tid >> 6;
    const int wr   = w >> 1;
    const int wc   = w & 1;
    const int lrow = lane & 15;
    const int kgrp = lane >> 4;

    const unsigned short* pa = Aws + ((size_t)h * TOTAL + row0 + tr * BT) * HSIZE;
    const unsigned short* pb = Bws + ((size_t)h * TOTAL + row0) * HSIZE;

    // ---- prologue: A panel -> lds0, B tile0 -> lds1 (16 loads in flight) ----
    {
        uint4 ga[8], gb[8];
        #pragma unroll
        for (int it = 0; it < 8; ++it) ga[it] = *(const uint4*)(pa + ((size_t)it * 256 + tid) * 8);
        #pragma unroll
        for (int it = 0; it < 8; ++it) gb[it] = *(const uint4*)(pb + ((size_t)it * 256 + tid) * 8);
        #pragma unroll
        for (int it = 0; it < 8; ++it)
            *(uint4*)&lds[0][(it * 16 + r0) * LDS_ROW + c8 * 8] = ga[it];
        #pragma unroll
        for (int it = 0; it < 8; ++it)
            *(uint4*)&lds[1][(it * 16 + r0) * LDS_ROW + c8 * 8] = gb[it];
    }
    __syncthreads();

    bf16x8 af[4][4];
    #pragma unroll
    for (int m = 0; m < 4; ++m)
        #pragma unroll
        for (int kk = 0; kk < 4; ++kk)
            af[m][kk] = *(const bf16x8*)&lds[0][(wr*64 + m*16 + lrow) * LDS_ROW + kk*32 + kgrp*8];
    __syncthreads();   // af reads done -> lds0 reusable as B buffer

    int cur = 1;
    const long long obase = map.out_off[i] + (long long)h * s * s;
    float* orow = out + obase
                + (long long)(tr * BT + wr * 64 + kgrp * 4) * s
                + (wc * 64 + lrow);

    const unsigned short* pbnext = pb + (size_t)BT * HSIZE;   // tile 1

    for (int tc = 0; tc < t; ++tc) {
        const bool has_next = (tc + 1 < t);

        // 1) issue next B-tile loads: 8x uint4, fully linear 32 KB block
        uint4 g[8];
        if (has_next) {
            #pragma unroll
            for (int it = 0; it < 8; ++it) g[it] = *(const uint4*)(pbnext + ((size_t)it * 256 + tid) * 8);
        }

        // 2) MFMA from lds[cur] (r3's unswapped operand order)
        f32x4 acc[4][4];
        #pragma unroll
        for (int m = 0; m < 4; ++m)
            #pragma unroll
            for (int n = 0; n < 4; ++n)
                acc[m][n] = (f32x4){0.f, 0.f, 0.f, 0.f};

        const unsigned short* lb = &lds[cur][0];
        #pragma unroll
        for (int kk = 0; kk < 4; ++kk) {
            bf16x8 bfr[4];
            #pragma unroll
            for (int n = 0; n < 4; ++n)
                bfr[n] = *(const bf16x8*)&lb[(wc*64 + n*16 + lrow) * LDS_ROW + kk*32 + kgrp*8];
            #pragma unroll
            for (int m = 0; m < 4; ++m)
                #pragma unroll
                for (int n = 0; n < 4; ++n)
                    acc[m][n] = __builtin_amdgcn_mfma_f32_16x16x32_bf16(
                                    af[m][kk], bfr[n], acc[m][n], 0, 0, 0);
        }

        // 3) write next B tile into the other buffer (no cvt — already bf16)
        if (has_next) {
            #pragma unroll
            for (int it = 0; it < 8; ++it)
                *(uint4*)&lds[cur ^ 1][(it * 16 + r0) * LDS_ROW + c8 * 8] = g[it];
            pbnext += (size_t)BT * HSIZE;
        }

        // 4) store C tile: r3's proven unswapped scalar pattern
        {
            float* op = orow + tc * BT;
            #pragma unroll
            for (int m = 0; m < 4; ++m)
                #pragma unroll
                for (int n = 0; n < 4; ++n)
                    #pragma unroll
                    for (int j = 0; j < 4; ++j)
                        op[(long long)(m * 16 + j) * s + n * 16] = acc[m][n][j];
        }

        __syncthreads();
        cur ^= 1;
    }
}

// ---- fallback: verbatim r3-strip (170 us) if ws is too small ----
__global__ __launch_bounds__(256, 2) void qkt_strip_kernel(
    const float* __restrict__ A, const float* __restrict__ B,
    float* __restrict__ out, SeqMap map)
{
    __shared__ unsigned short lds[2][BT * LDS_ROW];

    const int cpx = map.nblk >> 3;
    const int bid = ((int)blockIdx.x % 8) * cpx + ((int)blockIdx.x / 8);

    int i = 0;
    #pragma unroll
    for (int k = 1; k < NSEQ; ++k) if (bid >= map.blk_start[k]) i = k;
    const int local = bid - map.blk_start[i];
    const int t     = map.t[i];
    const int h     = local / t;
    const int tr    = local - h * t;
    const int s     = map.s[i];
    const int row0  = map.row_off[i];

    const int tid  = threadIdx.x;
    const int r0   = tid >> 5;
    const int c4   = tid & 31;
    const size_t hcol = (size_t)h * HSIZE + (size_t)c4 * 4;

    const int lane = tid & 63;
    const int w    = tid >> 6;
    const int wr   = w >> 1;
    const int wc   = w & 1;
    const int lrow = lane & 15;
    const int kgrp = lane >> 4;

    unsigned short* ldsw0 = &lds[0][r0 * LDS_ROW + c4 * 4];
    unsigned short* ldsw1 = &lds[1][r0 * LDS_ROW + c4 * 4];

    {
        const float* sa = A + (size_t)(row0 + tr * BT + r0) * HIDDEN + hcol;
        const float* sb = B + (size_t)(row0 + r0) * HIDDEN + hcol;
        float4 ga[16], gb[16];
        #pragma unroll
        for (int it = 0; it < 16; ++it) ga[it] = *(const float4*)(sa + (size_t)it * 8 * HIDDEN);
        #pragma unroll
        for (int it = 0; it < 16; ++it) gb[it] = *(const float4*)(sb + (size_t)it * 8 * HIDDEN);
        #pragma unroll
        for (int it = 0; it < 16; ++it)
            *(ushort4*)(ldsw0 + it * 8 * LDS_ROW) = f2bf4(ga[it]);
        #pragma unroll
        for (int it = 0; it < 16; ++it)
            *(ushort4*)(ldsw1 + it * 8 * LDS_ROW) = f2bf4(gb[it]);
    }
    __syncthreads();

    bf16x8 af[4][4];
    #pragma unroll
    for (int m = 0; m < 4; ++m)
        #pragma unroll
        for (int kk = 0; kk < 4; ++kk)
            af[m][kk] = *(const bf16x8*)&lds[0][(wr*64 + m*16 + lrow) * LDS_ROW + kk*32 + kgrp*8];
    __syncthreads();

    int cur = 1;
    const long long obase = map.out_off[i] + (long long)h * s * s;
    float* orow = out + obase
                + (long long)(tr * BT + wr * 64 + kgrp * 4) * s
                + (wc * 64 + lrow);

    const float* sbnext = B + (size_t)(row0 + BT + r0) * HIDDEN + hcol;

    for (int tc = 0; tc < t; ++tc) {
        const bool has_next = (tc + 1 < t);

        float4 g[16];
        if (has_next) {
            #pragma unroll
            for (int it = 0; it < 16; ++it) g[it] = *(const float4*)(sbnext + (size_t)it * 8 * HIDDEN);
        }

        f32x4 acc[4][4];
        #pragma unroll
        for (int m = 0; m < 4; ++m)
            #pragma unroll
            for (int n = 0; n < 4; ++n)
                acc[m][n] = (f32x4){0.f, 0.f, 0.f, 0.f};

        const unsigned short* lb = &lds[cur][0];
        #pragma unroll
        for (int kk = 0; kk < 4; ++kk) {
            bf16x8 bfr[4];
            #pragma unroll
            for (int n = 0; n < 4; ++n)
                bfr[n] = *(const bf16x8*)&lb[(wc*64 + n*16 + lrow) * LDS_ROW + kk*32 + kgrp*8];
            #pragma unroll
            for (int m = 0; m < 4; ++m)
                #pragma unroll
                for (int n = 0; n < 4; ++n)
                    acc[m][n] = __builtin_amdgcn_mfma_f32_16x16x32_bf16(
                                    af[m][kk], bfr[n], acc[m][n], 0, 0, 0);
        }

        if (has_next) {
            unsigned short* dst = cur ? ldsw0 : ldsw1;
            #pragma unroll
            for (int it = 0; it < 16; ++it)
                *(ushort4*)(dst + it * 8 * LDS_ROW) = f2bf4(g[it]);
            sbnext += (size_t)BT * HIDDEN;
        }

        {
            float* op = orow + tc * BT;
            #pragma unroll
            for (int m = 0; m < 4; ++m)
                #pragma unroll
                for (int n = 0; n < 4; ++n)
                    #pragma unroll
                    for (int j = 0; j < 4; ++j)
                        op[(long long)(m * 16 + j) * s + n * 16] = acc[m][n][j];
        }

        __syncthreads();
        cur ^= 1;
    }
}

extern "C" void kernel_launch(void* const* d_in, const int* in_sizes, int n_in,
                              void* d_out, int out_size, void* d_ws, size_t ws_size,
                              hipStream_t stream) {
    const float* A = (const float*)d_in[0];
    const float* B = (const float*)d_in[1];
    float* out = (float*)d_out;

    static const int S[NSEQ] = {1024, 768, 512, 1536, 256, 1280, 512, 1024};

    int row_off[NSEQ]; long long out_off[NSEQ];
    int row = 0; long long o = 0;
    for (int i = 0; i < NSEQ; ++i) {
        row_off[i] = row; out_off[i] = o;
        row += S[i];
        o   += (long long)HEADS * S[i] * S[i];
    }

    static const int order[NSEQ] = {3, 5, 0, 7, 1, 2, 6, 4};

    SeqMap map;
    int blk = 0;
    for (int k = 0; k < NSEQ; ++k) {
        const int i = order[k];
        const int t = S[i] / BT;
        map.s[k]         = S[i];
        map.row_off[k]   = row_off[i];
        map.out_off[k]   = out_off[i];
        map.t[k]         = t;
        map.blk_start[k] = blk;
        blk += HEADS * t;
    }
    map.nblk = blk;   // 864, % 8 == 0

    const size_t need = (size_t)2 * TOTAL * HIDDEN * sizeof(unsigned short); // 56.6 MB
    if (ws_size >= need) {
        unsigned short* Aws = (unsigned short*)d_ws;
        unsigned short* Bws = Aws + (size_t)TOTAL * HIDDEN;
        precvt_kernel<<<2048, 256, 0, stream>>>(A, B, Aws, Bws);
        qkt_bf16_kernel<<<blk, 256, 0, stream>>>(Aws, Bws, out, map);
    } else {
        qkt_strip_kernel<<<blk, 256, 0, stream>>>(A, B, out, map);
    }
}

// Round 12
// 184.143 us; speedup vs baseline: 1.6062x; 1.3372x over previous
//
#include <hip/hip_runtime.h>

#define NSEQ   8
#define HEADS  16
#define HSIZE  128          // head_size = 2048/16
#define HIDDEN 2048
#define BT     128          // tile edge
#define TOTAL  6912         // sum(seqlen); all row offsets are %128==0
#define LDS_PAD 8
#define LDS_ROW (HSIZE + LDS_PAD)   // fallback kernel only

typedef __attribute__((ext_vector_type(8))) short          bf16x8;
typedef __attribute__((ext_vector_type(8))) unsigned short u16x8;
typedef __attribute__((ext_vector_type(4))) float          f32x4;

struct SeqMap {
    int       s[NSEQ];
    int       row_off[NSEQ];
    long long out_off[NSEQ];
    int       t[NSEQ];
    int       blk_start[NSEQ];
    int       nblk;
};

__device__ __forceinline__ unsigned short f2bf(float x) {
    unsigned int u = __builtin_bit_cast(unsigned int, x);
    u += 0x7fffu + ((u >> 16) & 1u);
    return (unsigned short)(u >> 16);
}

__device__ __forceinline__ ushort4 f2bf4(float4 v) {
    ushort4 p;
    p.x = f2bf(v.x); p.y = f2bf(v.y); p.z = f2bf(v.z); p.w = f2bf(v.w);
    return p;
}

// async global->LDS, 16B per lane; LDS dest = wave-uniform base + lane*16
__device__ __forceinline__ void gload_lds16(const void* g, void* l) {
    __builtin_amdgcn_global_load_lds(
        (const __attribute__((address_space(1))) unsigned int*)g,
        (__attribute__((address_space(3))) unsigned int*)l, 16, 0, 0);
}

// ---- pass 1: f32 [TOTAL][2048] -> bf16 ws [head][TOTAL][128], PRE-SWIZZLED ----
// Within each 256B row: 16B block at colbyte c16*16 holds source cols
// (c16*16 ^ ((row&7)<<4)) — the involution the main kernel applies on ds_read.
__global__ __launch_bounds__(256) void precvt_kernel(
    const float* __restrict__ A, const float* __restrict__ B,
    unsigned short* __restrict__ Aws, unsigned short* __restrict__ Bws)
{
    const int NG = HEADS * TOTAL * 16;              // 16B granules per matrix
    for (int idx = blockIdx.x * 256 + threadIdx.x; idx < 2 * NG;
         idx += gridDim.x * 256) {
        const int m  = idx >= NG;
        const int d  = m ? idx - NG : idx;
        const float* src = m ? B : A;
        unsigned short* dst = m ? Bws : Aws;

        const int c16  = d & 15;
        const int rw   = d >> 4;
        const int h    = rw / TOTAL;
        const int grow = rw - h * TOTAL;
        // fp32 element col within the head (8 floats, 8-aligned after XOR)
        const int colf = (c16 * 8) ^ ((grow & 7) << 3);

        const float* sp = src + (size_t)grow * HIDDEN + h * HSIZE + colf;
        float4 v0 = *(const float4*)sp;
        float4 v1 = *(const float4*)(sp + 4);
        ushort4 p0 = f2bf4(v0), p1 = f2bf4(v1);
        u16x8 o;
        o[0]=p0.x; o[1]=p0.y; o[2]=p0.z; o[3]=p0.w;
        o[4]=p1.x; o[5]=p1.y; o[6]=p1.z; o[7]=p1.w;
        *(u16x8*)(dst + ((size_t)h * TOTAL + grow) * HSIZE + c16 * 8) = o;
    }
}

// ---- pass 2: global_load_lds staging, swizzled ds_read, r3 compute/store ----
__global__ __launch_bounds__(256, 2) void qkt_glds_kernel(
    const unsigned short* __restrict__ Aws, const unsigned short* __restrict__ Bws,
    float* __restrict__ out, SeqMap map)
{
    __shared__ unsigned short lds[2][BT * HSIZE];   // 2 x 32 KB linear

    const int cpx = map.nblk >> 3;
    const int bid = ((int)blockIdx.x % 8) * cpx + ((int)blockIdx.x / 8);

    int i = 0;
    #pragma unroll
    for (int k = 1; k < NSEQ; ++k) if (bid >= map.blk_start[k]) i = k;
    const int local = bid - map.blk_start[i];
    const int t     = map.t[i];
    const int h     = local / t;
    const int tr    = local - h * t;
    const int s     = map.s[i];
    const int row0  = map.row_off[i];

    const int tid  = threadIdx.x;
    const int lane = tid & 63;
    const int w    = tid >> 6;
    const int wr   = w >> 1;
    const int wc   = w & 1;
    const int lrow = lane & 15;
    const int kgrp = lane >> 4;

    const unsigned short* paT    = Aws + ((size_t)h * TOTAL + row0 + tr * BT) * HSIZE;
    const unsigned short* pbBase = Bws + ((size_t)h * TOTAL + row0) * HSIZE;

    // wave w stages 8 x 1KB chunks: chunk (w*8+i), lanes auto-scatter 16B each
#define STAGE(buf, src) do {                                                   \
        _Pragma("unroll")                                                      \
        for (int i_ = 0; i_ < 8; ++i_)                                         \
            gload_lds16((src) + (size_t)(w * 8 + i_) * 512 + lane * 8,         \
                        &lds[buf][(w * 8 + i_) * 512]);                        \
    } while (0)

    // ---- prologue ----
    STAGE(0, paT);       // A tile -> lds0
    STAGE(1, pbBase);    // B0     -> lds1
    __syncthreads();     // vmcnt(0): both resident

    bf16x8 af[4][4];     // swizzled reads: byte = r*256 + ((kk*64+kgrp*16) ^ ((r&7)<<4))
    #pragma unroll
    for (int m = 0; m < 4; ++m) {
        const int r  = wr * 64 + m * 16 + lrow;
        const int x  = (r & 7) << 4;
        const char* rp = (const char*)&lds[0][0] + r * 256;
        #pragma unroll
        for (int kk = 0; kk < 4; ++kk)
            af[m][kk] = *(const bf16x8*)(rp + ((kk * 64 + kgrp * 16) ^ x));
    }
    __syncthreads();     // af reads done -> lds0 reusable

    if (t > 1) STAGE(0, pbBase + (size_t)BT * HSIZE);   // B1 -> lds0 (in flight)
    int cur = 1;

    const long long obase = map.out_off[i] + (long long)h * s * s;
    float* orow = out + obase
                + (long long)(tr * BT + wr * 64 + kgrp * 4) * s
                + (wc * 64 + lrow);

    for (int tc = 0; tc < t; ++tc) {
        // MFMA from lds[cur] (B(tc) resident: confirmed by the last barrier)
        f32x4 acc[4][4];
        #pragma unroll
        for (int m = 0; m < 4; ++m)
            #pragma unroll
            for (int n = 0; n < 4; ++n)
                acc[m][n] = (f32x4){0.f, 0.f, 0.f, 0.f};

        const char* lb = (const char*)&lds[cur][0];
        #pragma unroll
        for (int kk = 0; kk < 4; ++kk) {
            bf16x8 bfr[4];
            #pragma unroll
            for (int n = 0; n < 4; ++n) {
                const int r = wc * 64 + n * 16 + lrow;
                bfr[n] = *(const bf16x8*)(lb + r * 256 +
                            ((kk * 64 + kgrp * 16) ^ ((r & 7) << 4)));
            }
            #pragma unroll
            for (int m = 0; m < 4; ++m)
                #pragma unroll
                for (int n = 0; n < 4; ++n)
                    acc[m][n] = __builtin_amdgcn_mfma_f32_16x16x32_bf16(
                                    af[m][kk], bfr[n], acc[m][n], 0, 0, 0);
        }

        // C stores: r3's verbatim pattern (lanes 0-15 = contiguous 64B run)
        {
            float* op = orow + tc * BT;
            #pragma unroll
            for (int m = 0; m < 4; ++m)
                #pragma unroll
                for (int n = 0; n < 4; ++n)
                    #pragma unroll
                    for (int j = 0; j < 4; ++j)
                        op[(long long)(m * 16 + j) * s + n * 16] = acc[m][n][j];
        }

        __syncthreads();   // vmcnt(0): B(tc+1) arrived; lds[cur] reads done

        // issue B(tc+2) into the buffer we just finished reading; it has the
        // whole next iteration (MFMA+stores+barrier) to land
        if (tc + 2 < t) STAGE(cur, pbBase + (size_t)(tc + 2) * BT * HSIZE);

        cur ^= 1;
    }
#undef STAGE
}

// ---- fallback: verbatim r3-strip (170 us) if ws is too small ----
__global__ __launch_bounds__(256, 2) void qkt_strip_kernel(
    const float* __restrict__ A, const float* __restrict__ B,
    float* __restrict__ out, SeqMap map)
{
    __shared__ unsigned short lds[2][BT * LDS_ROW];

    const int cpx = map.nblk >> 3;
    const int bid = ((int)blockIdx.x % 8) * cpx + ((int)blockIdx.x / 8);

    int i = 0;
    #pragma unroll
    for (int k = 1; k < NSEQ; ++k) if (bid >= map.blk_start[k]) i = k;
    const int local = bid - map.blk_start[i];
    const int t     = map.t[i];
    const int h     = local / t;
    const int tr    = local - h * t;
    const int s     = map.s[i];
    const int row0  = map.row_off[i];

    const int tid  = threadIdx.x;
    const int r0   = tid >> 5;
    const int c4   = tid & 31;
    const size_t hcol = (size_t)h * HSIZE + (size_t)c4 * 4;

    const int lane = tid & 63;
    const int w    = tid >> 6;
    const int wr   = w >> 1;
    const int wc   = w & 1;
    const int lrow = lane & 15;
    const int kgrp = lane >> 4;

    unsigned short* ldsw0 = &lds[0][r0 * LDS_ROW + c4 * 4];
    unsigned short* ldsw1 = &lds[1][r0 * LDS_ROW + c4 * 4];

    {
        const float* sa = A + (size_t)(row0 + tr * BT + r0) * HIDDEN + hcol;
        const float* sb = B + (size_t)(row0 + r0) * HIDDEN + hcol;
        float4 ga[16], gb[16];
        #pragma unroll
        for (int it = 0; it < 16; ++it) ga[it] = *(const float4*)(sa + (size_t)it * 8 * HIDDEN);
        #pragma unroll
        for (int it = 0; it < 16; ++it) gb[it] = *(const float4*)(sb + (size_t)it * 8 * HIDDEN);
        #pragma unroll
        for (int it = 0; it < 16; ++it)
            *(ushort4*)(ldsw0 + it * 8 * LDS_ROW) = f2bf4(ga[it]);
        #pragma unroll
        for (int it = 0; it < 16; ++it)
            *(ushort4*)(ldsw1 + it * 8 * LDS_ROW) = f2bf4(gb[it]);
    }
    __syncthreads();

    bf16x8 af[4][4];
    #pragma unroll
    for (int m = 0; m < 4; ++m)
        #pragma unroll
        for (int kk = 0; kk < 4; ++kk)
            af[m][kk] = *(const bf16x8*)&lds[0][(wr*64 + m*16 + lrow) * LDS_ROW + kk*32 + kgrp*8];
    __syncthreads();

    int cur = 1;
    const long long obase = map.out_off[i] + (long long)h * s * s;
    float* orow = out + obase
                + (long long)(tr * BT + wr * 64 + kgrp * 4) * s
                + (wc * 64 + lrow);

    const float* sbnext = B + (size_t)(row0 + BT + r0) * HIDDEN + hcol;

    for (int tc = 0; tc < t; ++tc) {
        const bool has_next = (tc + 1 < t);

        float4 g[16];
        if (has_next) {
            #pragma unroll
            for (int it = 0; it < 16; ++it) g[it] = *(const float4*)(sbnext + (size_t)it * 8 * HIDDEN);
        }

        f32x4 acc[4][4];
        #pragma unroll
        for (int m = 0; m < 4; ++m)
            #pragma unroll
            for (int n = 0; n < 4; ++n)
                acc[m][n] = (f32x4){0.f, 0.f, 0.f, 0.f};

        const unsigned short* lb = &lds[cur][0];
        #pragma unroll
        for (int kk = 0; kk < 4; ++kk) {
            bf16x8 bfr[4];
            #pragma unroll
            for (int n = 0; n < 4; ++n)
                bfr[n] = *(const bf16x8*)&lb[(wc*64 + n*16 + lrow) * LDS_ROW + kk*32 + kgrp*8];
            #pragma unroll
            for (int m = 0; m < 4; ++m)
                #pragma unroll
                for (int n = 0; n < 4; ++n)
                    acc[m][n] = __builtin_amdgcn_mfma_f32_16x16x32_bf16(
                                    af[m][kk], bfr[n], acc[m][n], 0, 0, 0);
        }

        if (has_next) {
            unsigned short* dst = cur ? ldsw0 : ldsw1;
            #pragma unroll
            for (int it = 0; it < 16; ++it)
                *(ushort4*)(dst + it * 8 * LDS_ROW) = f2bf4(g[it]);
            sbnext += (size_t)BT * HIDDEN;
        }

        {
            float* op = orow + tc * BT;
            #pragma unroll
            for (int m = 0; m < 4; ++m)
                #pragma unroll
                for (int n = 0; n < 4; ++n)
                    #pragma unroll
                    for (int j = 0; j < 4; ++j)
                        op[(long long)(m * 16 + j) * s + n * 16] = acc[m][n][j];
        }

        __syncthreads();
        cur ^= 1;
    }
}

extern "C" void kernel_launch(void* const* d_in, const int* in_sizes, int n_in,
                              void* d_out, int out_size, void* d_ws, size_t ws_size,
                              hipStream_t stream) {
    const float* A = (const float*)d_in[0];
    const float* B = (const float*)d_in[1];
    float* out = (float*)d_out;

    static const int S[NSEQ] = {1024, 768, 512, 1536, 256, 1280, 512, 1024};

    int row_off[NSEQ]; long long out_off[NSEQ];
    int row = 0; long long o = 0;
    for (int i = 0; i < NSEQ; ++i) {
        row_off[i] = row; out_off[i] = o;
        row += S[i];
        o   += (long long)HEADS * S[i] * S[i];
    }

    static const int order[NSEQ] = {3, 5, 0, 7, 1, 2, 6, 4};

    SeqMap map;
    int blk = 0;
    for (int k = 0; k < NSEQ; ++k) {
        const int i = order[k];
        const int t = S[i] / BT;
        map.s[k]         = S[i];
        map.row_off[k]   = row_off[i];
        map.out_off[k]   = out_off[i];
        map.t[k]         = t;
        map.blk_start[k] = blk;
        blk += HEADS * t;
    }
    map.nblk = blk;   // 864, % 8 == 0

    const size_t need = (size_t)2 * TOTAL * HIDDEN * sizeof(unsigned short); // 56.6 MB
    if (ws_size >= need) {
        unsigned short* Aws = (unsigned short*)d_ws;
        unsigned short* Bws = Aws + (size_t)TOTAL * HIDDEN;
        precvt_kernel<<<2048, 256, 0, stream>>>(A, B, Aws, Bws);
        qkt_glds_kernel<<<blk, 256, 0, stream>>>(Aws, Bws, out, map);
    } else {
        qkt_strip_kernel<<<blk, 256, 0, stream>>>(A, B, out, map);
    }
}